// Round 1
// baseline (98.429 us; speedup 1.0000x reference)
//
#include <hip/hip_runtime.h>

#define BATCH 262144
#define M 64

constexpr float KDT  = 1.0f / 48000.0f;
constexpr float EPSF = 1e-12f;

__global__ __launch_bounds__(256) void sav_kernel(
    const float* __restrict__ y0,
    const float* __restrict__ dp,
    const float* __restrict__ dm,
    const float* __restrict__ omega_sq,
    const float* __restrict__ mu_p,
    const float* __restrict__ Phi_e,
    const float* __restrict__ fe_points,
    const int*   __restrict__ n_p,
    float* __restrict__ out)
{
    const int lane = threadIdx.x & 63;
    const int wib  = threadIdx.x >> 6;          // wave in block (0..3)
    const int b    = blockIdx.x * 4 + wib;      // batch row
    if (b >= BATCH) return;

    const int   n  = *n_p;
    const float mu = *mu_p;

    // per-mode constants (cached in L1/L2, broadcast across blocks)
    const float dpi = dp[lane];
    const float dmi = dm[lane];
    const float osq = omega_sq[lane];
    const float phe = Phi_e[lane];

    const float* row = y0 + (size_t)b * (2 * M + 1);
    const float q0   = row[lane];          // coalesced 256B
    const float p0   = row[M + lane];      // coalesced 256B
    const float psi0 = row[2 * M];         // wave-broadcast load
    const float fe   = fe_points[(size_t)b * 16 + n];

    // q_half and g0
    const float qh = q0 + 0.5f * KDT * p0;
    const float q2 = qh * qh;
    const float q3 = q2 * qh;
    const float q4 = q2 * q2;

    float s = q4;                           // sum(q_half^4)
    #pragma unroll
    for (int o = 32; o > 0; o >>= 1) s += __shfl_xor(s, o, 64);
    const float potential = 0.25f * s;
    const float true_psi  = sqrtf(2.0f * potential + EPSF);
    const float g0 = -q3 / true_psi;

    const float a0 = 0.5f * KDT * mu * g0;
    const float b0 = a0 / dpi;

    // S1 = sum(a0*p0), S3 = sum(a0*b0)
    float s1 = a0 * p0;
    float s3 = a0 * b0;
    #pragma unroll
    for (int o = 32; o > 0; o >>= 1) {
        s1 += __shfl_xor(s1, o, 64);
        s3 += __shfl_xor(s3, o, 64);
    }

    // p1 pre-division (RHS of second assignment uses THIS p1)
    float p1 = dmi * p0 - a0 * s1
             + KDT * (-osq * qh - mu * mu * g0 * psi0 + phe * fe);

    // S2 = sum(b0 * p1_pre)
    float s2 = b0 * p1;
    #pragma unroll
    for (int o = 32; o > 0; o >>= 1) s2 += __shfl_xor(s2, o, 64);

    p1 = p1 / dpi - b0 * s2 / (1.0f + s3);

    // psi1 = psi0 + K * sum(g0 * 0.5*(p0+p1))
    float sg = g0 * (0.5f * (p0 + p1));
    #pragma unroll
    for (int o = 32; o > 0; o >>= 1) sg += __shfl_xor(sg, o, 64);
    const float psi1 = psi0 + KDT * sg;

    const float q1 = qh + 0.5f * KDT * p1;

    float* orow = out + (size_t)b * (2 * M + 1);
    orow[lane]     = q1;   // coalesced 256B
    orow[M + lane] = p1;   // coalesced 256B
    if (lane == 0) orow[2 * M] = psi1;
}

extern "C" void kernel_launch(void* const* d_in, const int* in_sizes, int n_in,
                              void* d_out, int out_size, void* d_ws, size_t ws_size,
                              hipStream_t stream) {
    const float* y0        = (const float*)d_in[0];
    const float* dp        = (const float*)d_in[1];
    const float* dm        = (const float*)d_in[2];
    const float* omega_sq  = (const float*)d_in[3];
    const float* mu        = (const float*)d_in[4];
    const float* Phi_e     = (const float*)d_in[5];
    const float* fe_points = (const float*)d_in[6];
    const int*   n_p       = (const int*)d_in[7];
    float* out = (float*)d_out;

    const int blocks = BATCH / 4;  // 4 waves (rows) per 256-thread block
    sav_kernel<<<blocks, 256, 0, stream>>>(y0, dp, dm, omega_sq, mu, Phi_e,
                                           fe_points, n_p, out);
}

// Round 2
// 64.781 us; speedup vs baseline: 1.5194x; 1.5194x over previous
//
#include <hip/hip_runtime.h>

#define BATCH 262144
#define M 64

constexpr float KDT  = 1.0f / 48000.0f;
constexpr float EPSF = 1e-12f;

// 4 rows per wave (16 lanes each), 4 modes per thread: m = sl + 16*j.
// All y0/out accesses are contiguous 64B per 16-lane subgroup per instruction.
__global__ __launch_bounds__(256) void sav_kernel(
    const float* __restrict__ y0,
    const float* __restrict__ dp,
    const float* __restrict__ dm,
    const float* __restrict__ omega_sq,
    const float* __restrict__ mu_p,
    const float* __restrict__ Phi_e,
    const float* __restrict__ fe_points,
    const int*   __restrict__ n_p,
    float* __restrict__ out)
{
    const int tid  = threadIdx.x;
    const int lane = tid & 63;
    const int sl   = lane & 15;        // sub-lane within row group
    const int sub  = lane >> 4;        // row within wave (0..3)
    const int wib  = tid >> 6;         // wave in block (0..3)
    const int b    = blockIdx.x * 16 + wib * 4 + sub;

    const int   n  = *n_p;
    const float mu = *mu_p;

    // per-mode constants (L1-hot, broadcast across blocks)
    float dpv[4], dmv[4], osq[4], phe[4];
    #pragma unroll
    for (int j = 0; j < 4; ++j) {
        const int m = sl + 16 * j;
        dpv[j] = dp[m];
        dmv[j] = dm[m];
        osq[j] = omega_sq[m];
        phe[j] = Phi_e[m];
    }

    const float* row = y0 + (size_t)b * (2 * M + 1);
    float q0v[4], p0v[4];
    #pragma unroll
    for (int j = 0; j < 4; ++j) {
        q0v[j] = row[sl + 16 * j];        // 64B contiguous per subgroup
        p0v[j] = row[M + sl + 16 * j];
    }
    const float psi0 = row[2 * M];        // broadcast within subgroup
    const float fe   = fe_points[(size_t)b * 16 + n];

    // q_half, powers, local sum of qh^4
    float qh[4], q3[4];
    float lq4 = 0.0f;
    #pragma unroll
    for (int j = 0; j < 4; ++j) {
        const float q = q0v[j] + 0.5f * KDT * p0v[j];
        const float q2 = q * q;
        qh[j] = q;
        q3[j] = q2 * q;
        lq4 += q2 * q2;
    }

    // butterfly A over 16 lanes: s = sum(qh^4)
    float s = lq4;
    #pragma unroll
    for (int o = 1; o < 16; o <<= 1) s += __shfl_xor(s, o, 64);

    // true_psi = sqrt(2*0.25*s + eps) -> inv via rsq
    const float inv_psi = __builtin_amdgcn_rsqf(0.5f * s + EPSF);

    const float c = 0.5f * KDT * mu;
    float g0[4], a0[4], b0[4], idp[4];
    float ls1 = 0.0f, ls3 = 0.0f;
    #pragma unroll
    for (int j = 0; j < 4; ++j) {
        g0[j]  = -q3[j] * inv_psi;
        a0[j]  = c * g0[j];
        idp[j] = __builtin_amdgcn_rcpf(dpv[j]);
        b0[j]  = a0[j] * idp[j];
        ls1 += a0[j] * p0v[j];
        ls3 += a0[j] * b0[j];
    }

    // butterfly B: s1 = sum(a0*p0), s3 = sum(a0*b0)
    float s1 = ls1, s3 = ls3;
    #pragma unroll
    for (int o = 1; o < 16; o <<= 1) {
        s1 += __shfl_xor(s1, o, 64);
        s3 += __shfl_xor(s3, o, 64);
    }

    // p1 pre-division (reference uses THIS value inside sum(b0*p1))
    const float mu2psi = mu * mu * psi0;
    float p1p[4];
    float ls2 = 0.0f;
    #pragma unroll
    for (int j = 0; j < 4; ++j) {
        p1p[j] = dmv[j] * p0v[j] - a0[j] * s1
               + KDT * (-osq[j] * qh[j] - mu2psi * g0[j] + phe[j] * fe);
        ls2 += b0[j] * p1p[j];
    }

    // butterfly C: s2 = sum(b0 * p1_pre)
    float s2 = ls2;
    #pragma unroll
    for (int o = 1; o < 16; o <<= 1) s2 += __shfl_xor(s2, o, 64);

    const float t = s2 * __builtin_amdgcn_rcpf(1.0f + s3);

    // final p1, local sum g0 * p_half
    float p1[4];
    float lsg = 0.0f;
    #pragma unroll
    for (int j = 0; j < 4; ++j) {
        p1[j] = p1p[j] * idp[j] - b0[j] * t;
        lsg += g0[j] * (0.5f * (p0v[j] + p1[j]));
    }

    // butterfly D: sg = sum(g0 * p_half)
    float sg = lsg;
    #pragma unroll
    for (int o = 1; o < 16; o <<= 1) sg += __shfl_xor(sg, o, 64);

    const float psi1 = psi0 + KDT * sg;

    float* orow = out + (size_t)b * (2 * M + 1);
    #pragma unroll
    for (int j = 0; j < 4; ++j) {
        orow[sl + 16 * j]     = qh[j] + 0.5f * KDT * p1[j];  // q1
        orow[M + sl + 16 * j] = p1[j];
    }
    if (sl == 0) orow[2 * M] = psi1;
}

extern "C" void kernel_launch(void* const* d_in, const int* in_sizes, int n_in,
                              void* d_out, int out_size, void* d_ws, size_t ws_size,
                              hipStream_t stream) {
    const float* y0        = (const float*)d_in[0];
    const float* dp        = (const float*)d_in[1];
    const float* dm        = (const float*)d_in[2];
    const float* omega_sq  = (const float*)d_in[3];
    const float* mu        = (const float*)d_in[4];
    const float* Phi_e     = (const float*)d_in[5];
    const float* fe_points = (const float*)d_in[6];
    const int*   n_p       = (const int*)d_in[7];
    float* out = (float*)d_out;

    const int blocks = BATCH / 16;  // 4 waves/block x 4 rows/wave
    sav_kernel<<<blocks, 256, 0, stream>>>(y0, dp, dm, omega_sq, mu, Phi_e,
                                           fe_points, n_p, out);
}